// Round 1
// baseline (1269.262 us; speedup 1.0000x reference)
//
#include <hip/hip_runtime.h>

#define N_NODES 100000
#define N_EDGES 600000
#define DIM 128
#define N_GRAPHS 512
#define MLP_HID 12
#define N_CLASSES 10
#define NPB 8   // nodes per block in the node-GEMM kernel

// ---- Stage 1: degree accumulation ------------------------------------------
__global__ void deg_kernel(const int* __restrict__ src, const int* __restrict__ dst,
                           float* __restrict__ deg_out, float* __restrict__ deg_in) {
    int e = blockIdx.x * blockDim.x + threadIdx.x;
    if (e < N_EDGES) {
        atomicAdd(&deg_out[src[e]], 1.0f);
        atomicAdd(&deg_in[dst[e]], 1.0f);
    }
}

// ---- Stage 2: deg -> deg^-0.5 in place -------------------------------------
__global__ void norm_kernel(float* __restrict__ deg_out, float* __restrict__ deg_in) {
    int i = blockIdx.x * blockDim.x + threadIdx.x;
    if (i < N_NODES) {
        deg_out[i] = 1.0f / sqrtf(fmaxf(deg_out[i], 1.0f));
        deg_in[i]  = 1.0f / sqrtf(fmaxf(deg_in[i],  1.0f));
    }
}

// ---- Stage 3: edge scatter: agg[dst] += feats[src] * norm_src[src] ----------
// 32 threads per edge, float4 per thread (128 dims).
__global__ void scatter_kernel(const float* __restrict__ feats,
                               const int* __restrict__ src, const int* __restrict__ dst,
                               const float* __restrict__ norm_src,
                               float* __restrict__ agg) {
    long long t = (long long)blockIdx.x * blockDim.x + threadIdx.x;
    const long long total = (long long)N_EDGES * 32;
    if (t >= total) return;
    int e = (int)(t >> 5);
    int q = (int)(t & 31);
    int s = src[e];
    int d = dst[e];
    float ns = norm_src[s];
    const float4* fr = (const float4*)(feats + (long long)s * DIM);
    float4 v = fr[q];
    float* ar = agg + (long long)d * DIM + q * 4;
    atomicAdd(ar + 0, v.x * ns);
    atomicAdd(ar + 1, v.y * ns);
    atomicAdd(ar + 2, v.z * ns);
    atomicAdd(ar + 3, v.w * ns);
}

// ---- Stage 4: h = relu((agg*norm_dst) @ W + b); gsum[gid] += h; cnt[gid]++ --
__global__ __launch_bounds__(128) void gemm_relu_pool(
        const float* __restrict__ agg, const float* __restrict__ norm_dst,
        const float* __restrict__ W, const float* __restrict__ b,
        const int* __restrict__ gid,
        float* __restrict__ gsum, float* __restrict__ cnt) {
    __shared__ float s[NPB][DIM];
    int t = threadIdx.x;
    int node0 = blockIdx.x * NPB;

    #pragma unroll
    for (int j = 0; j < NPB; ++j) {
        int n = node0 + j;
        float v = 0.0f;
        if (n < N_NODES) v = agg[(long long)n * DIM + t] * norm_dst[n];
        s[j][t] = v;
    }
    __syncthreads();

    float acc[NPB];
    float bv = b[t];
    #pragma unroll
    for (int j = 0; j < NPB; ++j) acc[j] = bv;

    for (int k = 0; k < DIM; ++k) {
        float wv = W[k * DIM + t];
        #pragma unroll
        for (int j = 0; j < NPB; ++j) acc[j] = fmaf(s[j][k], wv, acc[j]);
    }

    // graph pooling. graph_ids is sorted -> blocks are usually graph-uniform:
    // pre-reduce across the 8 nodes to cut gsum atomics 8x.
    bool all_valid = (node0 + NPB <= N_NODES);
    if (all_valid) {
        int g0 = gid[node0];
        bool same = (gid[node0 + NPB - 1] == g0);  // sorted => all equal iff ends equal
        if (same) {
            float hs = 0.0f;
            #pragma unroll
            for (int j = 0; j < NPB; ++j) hs += fmaxf(acc[j], 0.0f);
            atomicAdd(&gsum[g0 * DIM + t], hs);
            if (t == 0) atomicAdd(&cnt[g0], (float)NPB);
            return;
        }
    }
    for (int j = 0; j < NPB; ++j) {
        int n = node0 + j;
        if (n < N_NODES) {
            float h = fmaxf(acc[j], 0.0f);
            int g = gid[n];
            atomicAdd(&gsum[g * DIM + t], h);
            if (t == 0) atomicAdd(&cnt[g], 1.0f);
        }
    }
}

// ---- Stage 5: hg = gsum/cnt (0 if empty); out = (hg@W1+b1)@W2+b2 ------------
__global__ __launch_bounds__(128) void mlp_kernel(
        const float* __restrict__ gsum, const float* __restrict__ cnt,
        const float* __restrict__ W1, const float* __restrict__ b1,
        const float* __restrict__ W2, const float* __restrict__ b2,
        float* __restrict__ out) {
    __shared__ float s[DIM];
    __shared__ float t1[MLP_HID];
    int g = blockIdx.x;
    int t = threadIdx.x;
    float c = cnt[g];
    s[t] = (c > 0.0f) ? (gsum[g * DIM + t] / c) : 0.0f;
    __syncthreads();
    if (t < MLP_HID) {
        float a = b1[t];
        for (int k = 0; k < DIM; ++k) a = fmaf(s[k], W1[k * MLP_HID + t], a);
        t1[t] = a;
    }
    __syncthreads();
    if (t < N_CLASSES) {
        float o = b2[t];
        #pragma unroll
        for (int j = 0; j < MLP_HID; ++j) o = fmaf(t1[j], W2[j * N_CLASSES + t], o);
        out[g * N_CLASSES + t] = o;
    }
}

extern "C" void kernel_launch(void* const* d_in, const int* in_sizes, int n_in,
                              void* d_out, int out_size, void* d_ws, size_t ws_size,
                              hipStream_t stream) {
    const float* feats = (const float*)d_in[0];
    const float* W     = (const float*)d_in[1];
    const float* b     = (const float*)d_in[2];
    const float* W1    = (const float*)d_in[3];
    const float* b1    = (const float*)d_in[4];
    const float* W2    = (const float*)d_in[5];
    const float* b2    = (const float*)d_in[6];
    const int*   src   = (const int*)d_in[7];
    const int*   dst   = (const int*)d_in[8];
    const int*   gid   = (const int*)d_in[9];
    float* out = (float*)d_out;

    char* ws = (char*)d_ws;
    float* deg_out = (float*)ws;  ws += (size_t)N_NODES * 4;          // becomes norm_src
    float* deg_in  = (float*)ws;  ws += (size_t)N_NODES * 4;          // becomes norm_dst
    float* agg     = (float*)ws;  ws += (size_t)N_NODES * DIM * 4;
    float* gsum    = (float*)ws;  ws += (size_t)N_GRAPHS * DIM * 4;
    float* cnt     = (float*)ws;  ws += (size_t)N_GRAPHS * 4;
    size_t zero_bytes = (size_t)(ws - (char*)d_ws);

    hipMemsetAsync(d_ws, 0, zero_bytes, stream);

    deg_kernel<<<(N_EDGES + 255) / 256, 256, 0, stream>>>(src, dst, deg_out, deg_in);
    norm_kernel<<<(N_NODES + 255) / 256, 256, 0, stream>>>(deg_out, deg_in);

    long long scatter_threads = (long long)N_EDGES * 32;
    int scatter_blocks = (int)((scatter_threads + 255) / 256);
    scatter_kernel<<<scatter_blocks, 256, 0, stream>>>(feats, src, dst, deg_out, agg);

    gemm_relu_pool<<<(N_NODES + NPB - 1) / NPB, 128, 0, stream>>>(
        agg, deg_in, W, b, gid, gsum, cnt);

    mlp_kernel<<<N_GRAPHS, 128, 0, stream>>>(gsum, cnt, W1, b1, W2, b2, out);
}

// Round 2
// 318.925 us; speedup vs baseline: 3.9798x; 3.9798x over previous
//
#include <hip/hip_runtime.h>

#define N_NODES 100000
#define N_EDGES 600000
#define DIM 128
#define N_GRAPHS 512
#define MLP_HID 12
#define N_CLASSES 10
#define NPB 8            // nodes per block in the fused kernel
#define SCAN_B 512
#define SCAN_NBLK ((N_NODES + SCAN_B - 1) / SCAN_B)   // 196

// ---- Stage 1: integer degree histograms ------------------------------------
__global__ void deg_kernel(const int* __restrict__ src, const int* __restrict__ dst,
                           int* __restrict__ out_hist, int* __restrict__ in_hist) {
    int e = blockIdx.x * blockDim.x + threadIdx.x;
    if (e < N_EDGES) {
        atomicAdd(&out_hist[src[e]], 1);
        atomicAdd(&in_hist[dst[e]], 1);
    }
}

// ---- Stage 2: norms from histograms ----------------------------------------
__global__ void norm_kernel(const int* __restrict__ out_hist, const int* __restrict__ in_hist,
                            float* __restrict__ norm_src, float* __restrict__ norm_dst) {
    int i = blockIdx.x * blockDim.x + threadIdx.x;
    if (i < N_NODES) {
        norm_src[i] = rsqrtf((float)max(out_hist[i], 1));
        norm_dst[i] = rsqrtf((float)max(in_hist[i], 1));
    }
}

// ---- Stage 3a: per-block exclusive scan of in_hist --------------------------
__global__ __launch_bounds__(SCAN_B) void scan_block(
        const int* __restrict__ in_hist, int* __restrict__ scanned,
        int* __restrict__ blocksums) {
    __shared__ int tmp[SCAN_B];
    int t = threadIdx.x;
    int i = blockIdx.x * SCAN_B + t;
    int v = (i < N_NODES) ? in_hist[i] : 0;
    tmp[t] = v;
    __syncthreads();
    for (int off = 1; off < SCAN_B; off <<= 1) {
        int x = tmp[t];
        int y = (t >= off) ? tmp[t - off] : 0;
        __syncthreads();
        tmp[t] = x + y;
        __syncthreads();
    }
    int incl = tmp[t];
    if (i < N_NODES) scanned[i] = incl - v;          // exclusive
    if (t == SCAN_B - 1) blocksums[blockIdx.x] = incl;
}

// ---- Stage 3b: exclusive scan of block sums (single block) ------------------
__global__ __launch_bounds__(256) void scan_sums(int* __restrict__ blocksums) {
    __shared__ int tmp[256];
    int t = threadIdx.x;
    int v = (t < SCAN_NBLK) ? blocksums[t] : 0;
    tmp[t] = v;
    __syncthreads();
    for (int off = 1; off < 256; off <<= 1) {
        int x = tmp[t];
        int y = (t >= off) ? tmp[t - off] : 0;
        __syncthreads();
        tmp[t] = x + y;
        __syncthreads();
    }
    if (t < SCAN_NBLK) blocksums[t] = tmp[t] - v;    // exclusive
}

// ---- Stage 3c: combine -> offsets + cursor ----------------------------------
__global__ __launch_bounds__(SCAN_B) void scan_add(
        const int* __restrict__ scanned, const int* __restrict__ blocksums,
        int* __restrict__ offsets, int* __restrict__ cursor) {
    int i = blockIdx.x * SCAN_B + threadIdx.x;
    if (i < N_NODES) {
        int o = scanned[i] + blocksums[blockIdx.x];
        offsets[i] = o;
        cursor[i] = o;
    }
    if (i == 0) offsets[N_NODES] = N_EDGES;
}

// ---- Stage 4: bucket edges by dst (atomic ticket) ---------------------------
__global__ void bucket_kernel(const int* __restrict__ src, const int* __restrict__ dst,
                              int* __restrict__ cursor, int* __restrict__ edge_src) {
    int e = blockIdx.x * blockDim.x + threadIdx.x;
    if (e < N_EDGES) {
        int d = dst[e];
        int pos = atomicAdd(&cursor[d], 1);
        edge_src[pos] = src[e];
    }
}

// ---- Stage 5: fused gather + norm + GEMM + ReLU + graph pool ----------------
__global__ __launch_bounds__(128) void fused_gemm(
        const float* __restrict__ feats,
        const int* __restrict__ offsets, const int* __restrict__ edge_src,
        const float* __restrict__ norm_src, const float* __restrict__ norm_dst,
        const float* __restrict__ W, const float* __restrict__ b,
        const int* __restrict__ gid,
        float* __restrict__ gsum, float* __restrict__ cnt) {
    __shared__ float tile[NPB][DIM];
    int t = threadIdx.x;
    int node0 = blockIdx.x * NPB;

    // Gather aggregated neighbor features straight into LDS.
    #pragma unroll
    for (int j = 0; j < NPB; ++j) {
        int n = node0 + j;
        float acc = 0.0f;
        if (n < N_NODES) {
            int beg = offsets[n];
            int end = offsets[n + 1];
            float nd = norm_dst[n];
            for (int e = beg; e < end; ++e) {
                int sn = edge_src[e];                 // uniform across block
                acc = fmaf(feats[(long long)sn * DIM + t], norm_src[sn], acc);
            }
            acc *= nd;
        }
        tile[j][t] = acc;
    }
    __syncthreads();

    float acc[NPB];
    float bv = b[t];
    #pragma unroll
    for (int j = 0; j < NPB; ++j) acc[j] = bv;

    for (int k = 0; k < DIM; ++k) {
        float wv = W[k * DIM + t];
        #pragma unroll
        for (int j = 0; j < NPB; ++j) acc[j] = fmaf(tile[j][k], wv, acc[j]);
    }

    // graph pooling; graph_ids sorted -> most blocks graph-uniform (8x fewer atomics)
    bool all_valid = (node0 + NPB <= N_NODES);
    if (all_valid) {
        int g0 = gid[node0];
        if (gid[node0 + NPB - 1] == g0) {
            float hs = 0.0f;
            #pragma unroll
            for (int j = 0; j < NPB; ++j) hs += fmaxf(acc[j], 0.0f);
            atomicAdd(&gsum[g0 * DIM + t], hs);
            if (t == 0) atomicAdd(&cnt[g0], (float)NPB);
            return;
        }
    }
    for (int j = 0; j < NPB; ++j) {
        int n = node0 + j;
        if (n < N_NODES) {
            float h = fmaxf(acc[j], 0.0f);
            int g = gid[n];
            atomicAdd(&gsum[g * DIM + t], h);
            if (t == 0) atomicAdd(&cnt[g], 1.0f);
        }
    }
}

// ---- Stage 6: hg = gsum/cnt (0 if empty); out = (hg@W1+b1)@W2+b2 ------------
__global__ __launch_bounds__(128) void mlp_kernel(
        const float* __restrict__ gsum, const float* __restrict__ cnt,
        const float* __restrict__ W1, const float* __restrict__ b1,
        const float* __restrict__ W2, const float* __restrict__ b2,
        float* __restrict__ out) {
    __shared__ float s[DIM];
    __shared__ float t1[MLP_HID];
    int g = blockIdx.x;
    int t = threadIdx.x;
    float c = cnt[g];
    s[t] = (c > 0.0f) ? (gsum[g * DIM + t] / c) : 0.0f;
    __syncthreads();
    if (t < MLP_HID) {
        float a = b1[t];
        for (int k = 0; k < DIM; ++k) a = fmaf(s[k], W1[k * MLP_HID + t], a);
        t1[t] = a;
    }
    __syncthreads();
    if (t < N_CLASSES) {
        float o = b2[t];
        #pragma unroll
        for (int j = 0; j < MLP_HID; ++j) o = fmaf(t1[j], W2[j * N_CLASSES + t], o);
        out[g * N_CLASSES + t] = o;
    }
}

extern "C" void kernel_launch(void* const* d_in, const int* in_sizes, int n_in,
                              void* d_out, int out_size, void* d_ws, size_t ws_size,
                              hipStream_t stream) {
    const float* feats = (const float*)d_in[0];
    const float* W     = (const float*)d_in[1];
    const float* b     = (const float*)d_in[2];
    const float* W1    = (const float*)d_in[3];
    const float* b1    = (const float*)d_in[4];
    const float* W2    = (const float*)d_in[5];
    const float* b2    = (const float*)d_in[6];
    const int*   src   = (const int*)d_in[7];
    const int*   dst   = (const int*)d_in[8];
    const int*   gid   = (const int*)d_in[9];
    float* out = (float*)d_out;

    char* ws = (char*)d_ws;
    // --- zero-initialized region (one small memset) ---
    int*   out_hist = (int*)ws;   ws += (size_t)N_NODES * 4;
    int*   in_hist  = (int*)ws;   ws += (size_t)N_NODES * 4;
    float* gsum     = (float*)ws; ws += (size_t)N_GRAPHS * DIM * 4;
    float* cnt      = (float*)ws; ws += (size_t)N_GRAPHS * 4;
    size_t zero_bytes = (size_t)(ws - (char*)d_ws);
    // --- fully-overwritten region (no init needed) ---
    float* norm_src  = (float*)ws; ws += (size_t)N_NODES * 4;
    float* norm_dst  = (float*)ws; ws += (size_t)N_NODES * 4;
    int*   scanned   = (int*)ws;   ws += (size_t)N_NODES * 4;
    int*   blocksums = (int*)ws;   ws += 256 * 4;
    int*   offsets   = (int*)ws;   ws += ((size_t)N_NODES + 1) * 4;
    ws = (char*)(((uintptr_t)ws + 15) & ~(uintptr_t)15);
    int*   cursor    = (int*)ws;   ws += (size_t)N_NODES * 4;
    int*   edge_src  = (int*)ws;   ws += (size_t)N_EDGES * 4;

    hipMemsetAsync(d_ws, 0, zero_bytes, stream);

    deg_kernel<<<(N_EDGES + 255) / 256, 256, 0, stream>>>(src, dst, out_hist, in_hist);
    norm_kernel<<<(N_NODES + 255) / 256, 256, 0, stream>>>(out_hist, in_hist, norm_src, norm_dst);

    scan_block<<<SCAN_NBLK, SCAN_B, 0, stream>>>(in_hist, scanned, blocksums);
    scan_sums<<<1, 256, 0, stream>>>(blocksums);
    scan_add<<<SCAN_NBLK, SCAN_B, 0, stream>>>(scanned, blocksums, offsets, cursor);

    bucket_kernel<<<(N_EDGES + 255) / 256, 256, 0, stream>>>(src, dst, cursor, edge_src);

    fused_gemm<<<(N_NODES + NPB - 1) / NPB, 128, 0, stream>>>(
        feats, offsets, edge_src, norm_src, norm_dst, W, b, gid, gsum, cnt);

    mlp_kernel<<<N_GRAPHS, 128, 0, stream>>>(gsum, cnt, W1, b1, W2, b2, out);
}

// Round 3
// 309.555 us; speedup vs baseline: 4.1003x; 1.0303x over previous
//
#include <hip/hip_runtime.h>

#define N_NODES 100000
#define N_EDGES 600000
#define DIM 128
#define N_GRAPHS 512
#define MLP_HID 12
#define N_CLASSES 10
#define NPB 8            // nodes per block in the fused kernel
#define SCAN_B 512
#define SCAN_NBLK ((N_NODES + SCAN_B - 1) / SCAN_B)   // 196

// ---- Stage 1: integer degree histograms (int4-vectorized edges) -------------
__global__ void deg_kernel(const int4* __restrict__ src4, const int4* __restrict__ dst4,
                           int* __restrict__ out_hist, int* __restrict__ in_hist) {
    int i = blockIdx.x * blockDim.x + threadIdx.x;
    if (i < N_EDGES / 4) {
        int4 s = src4[i];
        int4 d = dst4[i];
        atomicAdd(&out_hist[s.x], 1); atomicAdd(&out_hist[s.y], 1);
        atomicAdd(&out_hist[s.z], 1); atomicAdd(&out_hist[s.w], 1);
        atomicAdd(&in_hist[d.x], 1);  atomicAdd(&in_hist[d.y], 1);
        atomicAdd(&in_hist[d.z], 1);  atomicAdd(&in_hist[d.w], 1);
    }
}

// ---- Stage 2a: per-block exclusive scan of in_hist --------------------------
__global__ __launch_bounds__(SCAN_B) void scan_block(
        const int* __restrict__ in_hist, int* __restrict__ scanned,
        int* __restrict__ blocksums) {
    __shared__ int tmp[SCAN_B];
    int t = threadIdx.x;
    int i = blockIdx.x * SCAN_B + t;
    int v = (i < N_NODES) ? in_hist[i] : 0;
    tmp[t] = v;
    __syncthreads();
    for (int off = 1; off < SCAN_B; off <<= 1) {
        int x = tmp[t];
        int y = (t >= off) ? tmp[t - off] : 0;
        __syncthreads();
        tmp[t] = x + y;
        __syncthreads();
    }
    int incl = tmp[t];
    if (i < N_NODES) scanned[i] = incl - v;          // exclusive
    if (t == SCAN_B - 1) blocksums[blockIdx.x] = incl;
}

// ---- Stage 2b: exclusive scan of block sums (single block) ------------------
__global__ __launch_bounds__(256) void scan_sums(int* __restrict__ blocksums) {
    __shared__ int tmp[256];
    int t = threadIdx.x;
    int v = (t < SCAN_NBLK) ? blocksums[t] : 0;
    tmp[t] = v;
    __syncthreads();
    for (int off = 1; off < 256; off <<= 1) {
        int x = tmp[t];
        int y = (t >= off) ? tmp[t - off] : 0;
        __syncthreads();
        tmp[t] = x + y;
        __syncthreads();
    }
    if (t < SCAN_NBLK) blocksums[t] = tmp[t] - v;    // exclusive
}

// ---- Stage 2c: combine -> offsets + cursor, and both norms ------------------
__global__ __launch_bounds__(SCAN_B) void scan_add_norm(
        const int* __restrict__ scanned, const int* __restrict__ blocksums,
        const int* __restrict__ out_hist, const int* __restrict__ in_hist,
        int* __restrict__ offsets, int* __restrict__ cursor,
        float* __restrict__ norm_src, float* __restrict__ norm_dst) {
    int i = blockIdx.x * SCAN_B + threadIdx.x;
    if (i < N_NODES) {
        int o = scanned[i] + blocksums[blockIdx.x];
        offsets[i] = o;
        cursor[i] = o;
        norm_src[i] = rsqrtf((float)max(out_hist[i], 1));
        norm_dst[i] = rsqrtf((float)max(in_hist[i], 1));
    }
    if (i == 0) offsets[N_NODES] = N_EDGES;
}

// ---- Stage 3: bucket edges by dst (atomic ticket, int4 edge loads) ----------
__global__ void bucket_kernel(const int4* __restrict__ src4, const int4* __restrict__ dst4,
                              int* __restrict__ cursor, int* __restrict__ edge_src) {
    int i = blockIdx.x * blockDim.x + threadIdx.x;
    if (i < N_EDGES / 4) {
        int4 s = src4[i];
        int4 d = dst4[i];
        edge_src[atomicAdd(&cursor[d.x], 1)] = s.x;
        edge_src[atomicAdd(&cursor[d.y], 1)] = s.y;
        edge_src[atomicAdd(&cursor[d.z], 1)] = s.z;
        edge_src[atomicAdd(&cursor[d.w], 1)] = s.w;
    }
}

// ---- Stage 4: fused gather + norm + GEMM + ReLU + graph pool ----------------
// 128 threads = 4 gather-groups of 32 lanes (float4/lane over DIM=128).
__global__ __launch_bounds__(128) void fused_gemm(
        const float* __restrict__ feats,
        const int* __restrict__ offsets, const int* __restrict__ edge_src,
        const float* __restrict__ norm_src, const float* __restrict__ norm_dst,
        const float* __restrict__ W, const float* __restrict__ b,
        const int* __restrict__ gid,
        float* __restrict__ gsum, float* __restrict__ cnt) {
    __shared__ float tile[NPB][DIM];
    int t = threadIdx.x;
    int group = t >> 5;
    int lane = t & 31;
    int node0 = blockIdx.x * NPB;

    // Gather: 4 nodes in parallel per round, 2 rounds.
    #pragma unroll
    for (int r = 0; r < NPB / 4; ++r) {
        int j = r * 4 + group;
        int n = node0 + j;
        float4 acc = make_float4(0.f, 0.f, 0.f, 0.f);
        if (n < N_NODES) {
            int beg = offsets[n];
            int end = offsets[n + 1];
            for (int e0 = beg; e0 < end; e0 += 32) {
                int m = min(32, end - e0);
                int es = 0;
                float nsv = 0.0f;
                if (e0 + lane < end) {
                    es = edge_src[e0 + lane];
                    nsv = norm_src[es];
                }
                for (int i = 0; i < m; ++i) {
                    int sn = __shfl(es, i, 32);
                    float ns = __shfl(nsv, i, 32);
                    float4 f = ((const float4*)(feats + (long long)sn * DIM))[lane];
                    acc.x = fmaf(f.x, ns, acc.x);
                    acc.y = fmaf(f.y, ns, acc.y);
                    acc.z = fmaf(f.z, ns, acc.z);
                    acc.w = fmaf(f.w, ns, acc.w);
                }
            }
            float nd = norm_dst[n];
            acc.x *= nd; acc.y *= nd; acc.z *= nd; acc.w *= nd;
        }
        ((float4*)tile[j])[lane] = acc;
    }
    __syncthreads();

    // GEMM: acc[j][t] = sum_k tile[j][k] * W[k][t], vectorized LDS reads.
    float acc[NPB];
    float bv = b[t];
    #pragma unroll
    for (int j = 0; j < NPB; ++j) acc[j] = bv;

    for (int k4 = 0; k4 < DIM; k4 += 4) {
        float w0 = W[(k4 + 0) * DIM + t];
        float w1 = W[(k4 + 1) * DIM + t];
        float w2 = W[(k4 + 2) * DIM + t];
        float w3 = W[(k4 + 3) * DIM + t];
        #pragma unroll
        for (int j = 0; j < NPB; ++j) {
            float4 a = *(const float4*)&tile[j][k4];   // ds_read_b128 broadcast
            acc[j] = fmaf(a.x, w0, acc[j]);
            acc[j] = fmaf(a.y, w1, acc[j]);
            acc[j] = fmaf(a.z, w2, acc[j]);
            acc[j] = fmaf(a.w, w3, acc[j]);
        }
    }

    // graph pooling; graph_ids sorted -> most blocks graph-uniform
    bool all_valid = (node0 + NPB <= N_NODES);
    if (all_valid) {
        int g0 = gid[node0];
        if (gid[node0 + NPB - 1] == g0) {
            float hs = 0.0f;
            #pragma unroll
            for (int j = 0; j < NPB; ++j) hs += fmaxf(acc[j], 0.0f);
            atomicAdd(&gsum[g0 * DIM + t], hs);
            if (t == 0) atomicAdd(&cnt[g0], (float)NPB);
            return;
        }
    }
    for (int j = 0; j < NPB; ++j) {
        int n = node0 + j;
        if (n < N_NODES) {
            float h = fmaxf(acc[j], 0.0f);
            int g = gid[n];
            atomicAdd(&gsum[g * DIM + t], h);
            if (t == 0) atomicAdd(&cnt[g], 1.0f);
        }
    }
}

// ---- Stage 5: hg = gsum/cnt (0 if empty); out = (hg@W1+b1)@W2+b2 ------------
__global__ __launch_bounds__(128) void mlp_kernel(
        const float* __restrict__ gsum, const float* __restrict__ cnt,
        const float* __restrict__ W1, const float* __restrict__ b1,
        const float* __restrict__ W2, const float* __restrict__ b2,
        float* __restrict__ out) {
    __shared__ float s[DIM];
    __shared__ float t1[MLP_HID];
    int g = blockIdx.x;
    int t = threadIdx.x;
    float c = cnt[g];
    s[t] = (c > 0.0f) ? (gsum[g * DIM + t] / c) : 0.0f;
    __syncthreads();
    if (t < MLP_HID) {
        float a = b1[t];
        for (int k = 0; k < DIM; ++k) a = fmaf(s[k], W1[k * MLP_HID + t], a);
        t1[t] = a;
    }
    __syncthreads();
    if (t < N_CLASSES) {
        float o = b2[t];
        #pragma unroll
        for (int j = 0; j < MLP_HID; ++j) o = fmaf(t1[j], W2[j * N_CLASSES + t], o);
        out[g * N_CLASSES + t] = o;
    }
}

extern "C" void kernel_launch(void* const* d_in, const int* in_sizes, int n_in,
                              void* d_out, int out_size, void* d_ws, size_t ws_size,
                              hipStream_t stream) {
    const float* feats = (const float*)d_in[0];
    const float* W     = (const float*)d_in[1];
    const float* b     = (const float*)d_in[2];
    const float* W1    = (const float*)d_in[3];
    const float* b1    = (const float*)d_in[4];
    const float* W2    = (const float*)d_in[5];
    const float* b2    = (const float*)d_in[6];
    const int*   src   = (const int*)d_in[7];
    const int*   dst   = (const int*)d_in[8];
    const int*   gid   = (const int*)d_in[9];
    float* out = (float*)d_out;

    char* ws = (char*)d_ws;
    // --- zero-initialized region (one small memset) ---
    int*   out_hist = (int*)ws;   ws += (size_t)N_NODES * 4;
    int*   in_hist  = (int*)ws;   ws += (size_t)N_NODES * 4;
    float* gsum     = (float*)ws; ws += (size_t)N_GRAPHS * DIM * 4;
    float* cnt      = (float*)ws; ws += (size_t)N_GRAPHS * 4;
    size_t zero_bytes = (size_t)(ws - (char*)d_ws);
    // --- fully-overwritten region (no init needed) ---
    float* norm_src  = (float*)ws; ws += (size_t)N_NODES * 4;
    float* norm_dst  = (float*)ws; ws += (size_t)N_NODES * 4;
    int*   scanned   = (int*)ws;   ws += (size_t)N_NODES * 4;
    int*   blocksums = (int*)ws;   ws += 256 * 4;
    int*   offsets   = (int*)ws;   ws += ((size_t)N_NODES + 1) * 4;
    ws = (char*)(((uintptr_t)ws + 15) & ~(uintptr_t)15);
    int*   cursor    = (int*)ws;   ws += (size_t)N_NODES * 4;
    int*   edge_src  = (int*)ws;   ws += (size_t)N_EDGES * 4;

    hipMemsetAsync(d_ws, 0, zero_bytes, stream);

    deg_kernel<<<(N_EDGES / 4 + 255) / 256, 256, 0, stream>>>(
        (const int4*)src, (const int4*)dst, out_hist, in_hist);

    scan_block<<<SCAN_NBLK, SCAN_B, 0, stream>>>(in_hist, scanned, blocksums);
    scan_sums<<<1, 256, 0, stream>>>(blocksums);
    scan_add_norm<<<SCAN_NBLK, SCAN_B, 0, stream>>>(
        scanned, blocksums, out_hist, in_hist, offsets, cursor, norm_src, norm_dst);

    bucket_kernel<<<(N_EDGES / 4 + 255) / 256, 256, 0, stream>>>(
        (const int4*)src, (const int4*)dst, cursor, edge_src);

    fused_gemm<<<(N_NODES + NPB - 1) / NPB, 128, 0, stream>>>(
        feats, offsets, edge_src, norm_src, norm_dst, W, b, gid, gsum, cnt);

    mlp_kernel<<<N_GRAPHS, 128, 0, stream>>>(gsum, cnt, W1, b1, W2, b2, out);
}

// Round 4
// 292.023 us; speedup vs baseline: 4.3464x; 1.0600x over previous
//
#include <hip/hip_runtime.h>

#define N_NODES 100000
#define N_EDGES 600000
#define DIM 128
#define N_GRAPHS 512
#define MLP_HID 12
#define N_CLASSES 10
#define NPB 8            // nodes per block in the fused kernel
#define SCAN_B 512
#define SCAN_NBLK ((N_NODES + SCAN_B - 1) / SCAN_B)   // 196

// ---- Stage 1: integer degree histograms (int4-vectorized edges) -------------
__global__ void deg_kernel(const int4* __restrict__ src4, const int4* __restrict__ dst4,
                           int* __restrict__ out_hist, int* __restrict__ in_hist) {
    int i = blockIdx.x * blockDim.x + threadIdx.x;
    if (i < N_EDGES / 4) {
        int4 s = src4[i];
        int4 d = dst4[i];
        atomicAdd(&out_hist[s.x], 1); atomicAdd(&out_hist[s.y], 1);
        atomicAdd(&out_hist[s.z], 1); atomicAdd(&out_hist[s.w], 1);
        atomicAdd(&in_hist[d.x], 1);  atomicAdd(&in_hist[d.y], 1);
        atomicAdd(&in_hist[d.z], 1);  atomicAdd(&in_hist[d.w], 1);
    }
}

// ---- Stage 2a: per-block exclusive scan of in_hist --------------------------
__global__ __launch_bounds__(SCAN_B) void scan_block(
        const int* __restrict__ in_hist, int* __restrict__ scanned,
        int* __restrict__ blocksums) {
    __shared__ int tmp[SCAN_B];
    int t = threadIdx.x;
    int i = blockIdx.x * SCAN_B + t;
    int v = (i < N_NODES) ? in_hist[i] : 0;
    tmp[t] = v;
    __syncthreads();
    for (int off = 1; off < SCAN_B; off <<= 1) {
        int x = tmp[t];
        int y = (t >= off) ? tmp[t - off] : 0;
        __syncthreads();
        tmp[t] = x + y;
        __syncthreads();
    }
    int incl = tmp[t];
    if (i < N_NODES) scanned[i] = incl - v;          // exclusive
    if (t == SCAN_B - 1) blocksums[blockIdx.x] = incl;
}

// ---- Stage 2b: exclusive scan of block sums (single block) ------------------
__global__ __launch_bounds__(256) void scan_sums(int* __restrict__ blocksums) {
    __shared__ int tmp[256];
    int t = threadIdx.x;
    int v = (t < SCAN_NBLK) ? blocksums[t] : 0;
    tmp[t] = v;
    __syncthreads();
    for (int off = 1; off < 256; off <<= 1) {
        int x = tmp[t];
        int y = (t >= off) ? tmp[t - off] : 0;
        __syncthreads();
        tmp[t] = x + y;
        __syncthreads();
    }
    if (t < SCAN_NBLK) blocksums[t] = tmp[t] - v;    // exclusive
}

// ---- Stage 2c: combine -> offsets + cursor, and both norms ------------------
__global__ __launch_bounds__(SCAN_B) void scan_add_norm(
        const int* __restrict__ scanned, const int* __restrict__ blocksums,
        const int* __restrict__ out_hist, const int* __restrict__ in_hist,
        int* __restrict__ offsets, int* __restrict__ cursor,
        float* __restrict__ norm_src, float* __restrict__ norm_dst) {
    int i = blockIdx.x * SCAN_B + threadIdx.x;
    if (i < N_NODES) {
        int o = scanned[i] + blocksums[blockIdx.x];
        offsets[i] = o;
        cursor[i] = o;
        norm_src[i] = rsqrtf((float)max(out_hist[i], 1));
        norm_dst[i] = rsqrtf((float)max(in_hist[i], 1));
    }
    if (i == 0) offsets[N_NODES] = N_EDGES;
}

// ---- Stage 3: bucket edges by dst (atomic ticket, int4 edge loads) ----------
__global__ void bucket_kernel(const int4* __restrict__ src4, const int4* __restrict__ dst4,
                              int* __restrict__ cursor, int* __restrict__ edge_src) {
    int i = blockIdx.x * blockDim.x + threadIdx.x;
    if (i < N_EDGES / 4) {
        int4 s = src4[i];
        int4 d = dst4[i];
        edge_src[atomicAdd(&cursor[d.x], 1)] = s.x;
        edge_src[atomicAdd(&cursor[d.y], 1)] = s.y;
        edge_src[atomicAdd(&cursor[d.z], 1)] = s.z;
        edge_src[atomicAdd(&cursor[d.w], 1)] = s.w;
    }
}

// ---- Stage 4: fused gather + norm + GEMM + ReLU + graph pool ----------------
// 128 threads = 4 gather-groups of 32 lanes (float4/lane over DIM=128).
// Gather inner loop unrolled x4: 4 independent feats loads in flight per group.
__global__ __launch_bounds__(128) void fused_gemm(
        const float* __restrict__ feats,
        const int* __restrict__ offsets, const int* __restrict__ edge_src,
        const float* __restrict__ norm_src, const float* __restrict__ norm_dst,
        const float* __restrict__ W, const float* __restrict__ b,
        const int* __restrict__ gid,
        float* __restrict__ gsum, float* __restrict__ cnt) {
    __shared__ float tile[NPB][DIM];
    int t = threadIdx.x;
    int group = t >> 5;
    int lane = t & 31;
    int node0 = blockIdx.x * NPB;

    // Gather: 4 nodes in parallel per round, 2 rounds.
    #pragma unroll
    for (int r = 0; r < NPB / 4; ++r) {
        int j = r * 4 + group;
        int n = node0 + j;
        float4 acc = make_float4(0.f, 0.f, 0.f, 0.f);
        if (n < N_NODES) {
            int beg = offsets[n];
            int end = offsets[n + 1];
            for (int e0 = beg; e0 < end; e0 += 32) {
                int m = min(32, end - e0);
                int es = 0;
                float nsv = 0.0f;
                if (e0 + lane < end) {
                    es = edge_src[e0 + lane];
                    nsv = norm_src[es];
                }
                int i = 0;
                for (; i + 4 <= m; i += 4) {
                    int   sn0 = __shfl(es,  i + 0, 32), sn1 = __shfl(es,  i + 1, 32);
                    int   sn2 = __shfl(es,  i + 2, 32), sn3 = __shfl(es,  i + 3, 32);
                    float ns0 = __shfl(nsv, i + 0, 32), ns1 = __shfl(nsv, i + 1, 32);
                    float ns2 = __shfl(nsv, i + 2, 32), ns3 = __shfl(nsv, i + 3, 32);
                    float4 f0 = ((const float4*)(feats + (long long)sn0 * DIM))[lane];
                    float4 f1 = ((const float4*)(feats + (long long)sn1 * DIM))[lane];
                    float4 f2 = ((const float4*)(feats + (long long)sn2 * DIM))[lane];
                    float4 f3 = ((const float4*)(feats + (long long)sn3 * DIM))[lane];
                    acc.x = fmaf(f0.x, ns0, acc.x); acc.y = fmaf(f0.y, ns0, acc.y);
                    acc.z = fmaf(f0.z, ns0, acc.z); acc.w = fmaf(f0.w, ns0, acc.w);
                    acc.x = fmaf(f1.x, ns1, acc.x); acc.y = fmaf(f1.y, ns1, acc.y);
                    acc.z = fmaf(f1.z, ns1, acc.z); acc.w = fmaf(f1.w, ns1, acc.w);
                    acc.x = fmaf(f2.x, ns2, acc.x); acc.y = fmaf(f2.y, ns2, acc.y);
                    acc.z = fmaf(f2.z, ns2, acc.z); acc.w = fmaf(f2.w, ns2, acc.w);
                    acc.x = fmaf(f3.x, ns3, acc.x); acc.y = fmaf(f3.y, ns3, acc.y);
                    acc.z = fmaf(f3.z, ns3, acc.z); acc.w = fmaf(f3.w, ns3, acc.w);
                }
                for (; i + 2 <= m; i += 2) {
                    int   sn0 = __shfl(es,  i + 0, 32), sn1 = __shfl(es,  i + 1, 32);
                    float ns0 = __shfl(nsv, i + 0, 32), ns1 = __shfl(nsv, i + 1, 32);
                    float4 f0 = ((const float4*)(feats + (long long)sn0 * DIM))[lane];
                    float4 f1 = ((const float4*)(feats + (long long)sn1 * DIM))[lane];
                    acc.x = fmaf(f0.x, ns0, acc.x); acc.y = fmaf(f0.y, ns0, acc.y);
                    acc.z = fmaf(f0.z, ns0, acc.z); acc.w = fmaf(f0.w, ns0, acc.w);
                    acc.x = fmaf(f1.x, ns1, acc.x); acc.y = fmaf(f1.y, ns1, acc.y);
                    acc.z = fmaf(f1.z, ns1, acc.z); acc.w = fmaf(f1.w, ns1, acc.w);
                }
                for (; i < m; ++i) {
                    int   sn = __shfl(es,  i, 32);
                    float ns = __shfl(nsv, i, 32);
                    float4 f = ((const float4*)(feats + (long long)sn * DIM))[lane];
                    acc.x = fmaf(f.x, ns, acc.x); acc.y = fmaf(f.y, ns, acc.y);
                    acc.z = fmaf(f.z, ns, acc.z); acc.w = fmaf(f.w, ns, acc.w);
                }
            }
            float nd = norm_dst[n];
            acc.x *= nd; acc.y *= nd; acc.z *= nd; acc.w *= nd;
        }
        ((float4*)tile[j])[lane] = acc;
    }
    __syncthreads();

    // GEMM: acc[j][t] = sum_k tile[j][k] * W[k][t], vectorized LDS reads.
    float acc[NPB];
    float bv = b[t];
    #pragma unroll
    for (int j = 0; j < NPB; ++j) acc[j] = bv;

    for (int k4 = 0; k4 < DIM; k4 += 4) {
        float w0 = W[(k4 + 0) * DIM + t];
        float w1 = W[(k4 + 1) * DIM + t];
        float w2 = W[(k4 + 2) * DIM + t];
        float w3 = W[(k4 + 3) * DIM + t];
        #pragma unroll
        for (int j = 0; j < NPB; ++j) {
            float4 a = *(const float4*)&tile[j][k4];   // ds_read_b128 broadcast
            acc[j] = fmaf(a.x, w0, acc[j]);
            acc[j] = fmaf(a.y, w1, acc[j]);
            acc[j] = fmaf(a.z, w2, acc[j]);
            acc[j] = fmaf(a.w, w3, acc[j]);
        }
    }

    // graph pooling; graph_ids sorted -> most blocks graph-uniform
    bool all_valid = (node0 + NPB <= N_NODES);
    if (all_valid) {
        int g0 = gid[node0];
        if (gid[node0 + NPB - 1] == g0) {
            float hs = 0.0f;
            #pragma unroll
            for (int j = 0; j < NPB; ++j) hs += fmaxf(acc[j], 0.0f);
            atomicAdd(&gsum[g0 * DIM + t], hs);
            if (t == 0) atomicAdd(&cnt[g0], (float)NPB);
            return;
        }
    }
    for (int j = 0; j < NPB; ++j) {
        int n = node0 + j;
        if (n < N_NODES) {
            float h = fmaxf(acc[j], 0.0f);
            int g = gid[n];
            atomicAdd(&gsum[g * DIM + t], h);
            if (t == 0) atomicAdd(&cnt[g], 1.0f);
        }
    }
}

// ---- Stage 5: hg = gsum/cnt (0 if empty); out = (hg@W1+b1)@W2+b2 ------------
__global__ __launch_bounds__(128) void mlp_kernel(
        const float* __restrict__ gsum, const float* __restrict__ cnt,
        const float* __restrict__ W1, const float* __restrict__ b1,
        const float* __restrict__ W2, const float* __restrict__ b2,
        float* __restrict__ out) {
    __shared__ float s[DIM];
    __shared__ float t1[MLP_HID];
    int g = blockIdx.x;
    int t = threadIdx.x;
    float c = cnt[g];
    s[t] = (c > 0.0f) ? (gsum[g * DIM + t] / c) : 0.0f;
    __syncthreads();
    if (t < MLP_HID) {
        float a = b1[t];
        for (int k = 0; k < DIM; ++k) a = fmaf(s[k], W1[k * MLP_HID + t], a);
        t1[t] = a;
    }
    __syncthreads();
    if (t < N_CLASSES) {
        float o = b2[t];
        #pragma unroll
        for (int j = 0; j < MLP_HID; ++j) o = fmaf(t1[j], W2[j * N_CLASSES + t], o);
        out[g * N_CLASSES + t] = o;
    }
}

extern "C" void kernel_launch(void* const* d_in, const int* in_sizes, int n_in,
                              void* d_out, int out_size, void* d_ws, size_t ws_size,
                              hipStream_t stream) {
    const float* feats = (const float*)d_in[0];
    const float* W     = (const float*)d_in[1];
    const float* b     = (const float*)d_in[2];
    const float* W1    = (const float*)d_in[3];
    const float* b1    = (const float*)d_in[4];
    const float* W2    = (const float*)d_in[5];
    const float* b2    = (const float*)d_in[6];
    const int*   src   = (const int*)d_in[7];
    const int*   dst   = (const int*)d_in[8];
    const int*   gid   = (const int*)d_in[9];
    float* out = (float*)d_out;

    char* ws = (char*)d_ws;
    // --- zero-initialized region (one small memset) ---
    int*   out_hist = (int*)ws;   ws += (size_t)N_NODES * 4;
    int*   in_hist  = (int*)ws;   ws += (size_t)N_NODES * 4;
    float* gsum     = (float*)ws; ws += (size_t)N_GRAPHS * DIM * 4;
    float* cnt      = (float*)ws; ws += (size_t)N_GRAPHS * 4;
    size_t zero_bytes = (size_t)(ws - (char*)d_ws);
    // --- fully-overwritten region (no init needed) ---
    float* norm_src  = (float*)ws; ws += (size_t)N_NODES * 4;
    float* norm_dst  = (float*)ws; ws += (size_t)N_NODES * 4;
    int*   scanned   = (int*)ws;   ws += (size_t)N_NODES * 4;
    int*   blocksums = (int*)ws;   ws += 256 * 4;
    int*   offsets   = (int*)ws;   ws += ((size_t)N_NODES + 1) * 4;
    ws = (char*)(((uintptr_t)ws + 15) & ~(uintptr_t)15);
    int*   cursor    = (int*)ws;   ws += (size_t)N_NODES * 4;
    int*   edge_src  = (int*)ws;   ws += (size_t)N_EDGES * 4;

    hipMemsetAsync(d_ws, 0, zero_bytes, stream);

    deg_kernel<<<(N_EDGES / 4 + 255) / 256, 256, 0, stream>>>(
        (const int4*)src, (const int4*)dst, out_hist, in_hist);

    scan_block<<<SCAN_NBLK, SCAN_B, 0, stream>>>(in_hist, scanned, blocksums);
    scan_sums<<<1, 256, 0, stream>>>(blocksums);
    scan_add_norm<<<SCAN_NBLK, SCAN_B, 0, stream>>>(
        scanned, blocksums, out_hist, in_hist, offsets, cursor, norm_src, norm_dst);

    bucket_kernel<<<(N_EDGES / 4 + 255) / 256, 256, 0, stream>>>(
        (const int4*)src, (const int4*)dst, cursor, edge_src);

    fused_gemm<<<(N_NODES + NPB - 1) / NPB, 128, 0, stream>>>(
        feats, offsets, edge_src, norm_src, norm_dst, W, b, gid, gsum, cnt);

    mlp_kernel<<<N_GRAPHS, 128, 0, stream>>>(gsum, cnt, W1, b1, W2, b2, out);
}